// Round 1
// 134.543 us; speedup vs baseline: 1.0030x; 1.0030x over previous
//
#include <hip/hip_runtime.h>

#define NB 32   // batch
#define NT 50   // targets per image
#define NA 3    // anchors
#define NPAIR (NB * 3)

// Fused single-dispatch kernel.
// Blocks 0..95 (1 wave each): compute partial loss for (image b, scale s) pair,
//   publish to ws with a complement-validated flag (immune to any constant
//   re-poison pattern: no 32-bit word equals its own complement).
// Block 96: polls the 96 validated partials, reduces deterministically
//   (bitwise-identical order to the old 2-kernel version), writes d_out.
__global__ __launch_bounds__(64) void boxloss_fused_kernel(
    const float* __restrict__ out0, const float* __restrict__ anc0,
    const float* __restrict__ out1, const float* __restrict__ anc1,
    const float* __restrict__ out2, const float* __restrict__ anc2,
    const float* __restrict__ targets, float* __restrict__ ws,
    float* __restrict__ d_out)
{
    const int lane = threadIdx.x;
    unsigned* wsu = (unsigned*)ws;

    if (blockIdx.x == NPAIR) {
        // ---------------- reducer block ----------------
        float v0 = 0.f, v1 = 0.f;
        bool need0 = (lane < NPAIR);
        bool need1 = (lane + 64 < NPAIR);
        for (;;) {
            if (need0) {
                unsigned t = __hip_atomic_load(&wsu[2 * lane + 1],
                                               __ATOMIC_ACQUIRE, __HIP_MEMORY_SCOPE_AGENT);
                unsigned x = __hip_atomic_load(&wsu[2 * lane],
                                               __ATOMIC_RELAXED, __HIP_MEMORY_SCOPE_AGENT);
                if (t == ~x) { v0 = __uint_as_float(x); need0 = false; }
            }
            if (need1) {
                unsigned t = __hip_atomic_load(&wsu[2 * (lane + 64) + 1],
                                               __ATOMIC_ACQUIRE, __HIP_MEMORY_SCOPE_AGENT);
                unsigned x = __hip_atomic_load(&wsu[2 * (lane + 64)],
                                               __ATOMIC_RELAXED, __HIP_MEMORY_SCOPE_AGENT);
                if (t == ~x) { v1 = __uint_as_float(x); need1 = false; }
            }
            if (!__any(need0 || need1)) break;
            __builtin_amdgcn_s_sleep(1);
        }
        // identical arithmetic order to the old boxloss_reduce_kernel:
        float v = v0 + v1;
        #pragma unroll
        for (int off = 32; off >= 1; off >>= 1)
            v += __shfl_xor(v, off, 64);
        if (lane == 0) d_out[0] = v / (float)NB;
        return;
    }

    // ---------------- producer blocks ----------------
    const int pair = blockIdx.x;
    const int b = pair / 3;
    const int s = pair - 3 * b;
    const int g = (s == 0) ? 52 : (s == 1 ? 26 : 13);
    const float* outp = (s == 0) ? out0 : (s == 1 ? out1 : out2);
    const float* anc  = (s == 0) ? anc0 : (s == 1 ? anc1 : anc2);
    const float gf = (float)g;

    // Per-lane target processing (lane == target index j)
    int key = 0x40000000 + lane;   // unique sentinel: never collides with a real cell
    bool cand = false;
    float t0 = 0.f, t1 = 0.f, t2 = 0.f, t3 = 0.f;
    float p0 = 0.f, p1 = 0.f, p2 = 1.f, p3 = 1.f;

    if (lane < NT) {
        const float* tr = &targets[((size_t)b * NT + lane) * 5 + 1];
        float r0 = tr[0], r1 = tr[1], r2 = tr[2], r3 = tr[3];
        bool valid = !(r0 == 0.f && r1 == 0.f && r2 == 0.f && r3 == 0.f);
        t0 = r0 * gf; t1 = r1 * gf; t2 = r2 * gf; t3 = r3 * gf;
        float cx = floorf(t0), cy = floorf(t1);
        // zt = [t0-cx-0.5, t1-cy-0.5, t2, t3]; rect_t = xywh2rect(zt)
        float ztx = t0 - cx - 0.5f;
        float zty = t1 - cy - 0.5f;
        float tx0 = ztx - t2 * 0.5f, ty0 = zty - t3 * 0.5f;
        float tx1 = ztx + t2 * 0.5f, ty1 = zty + t3 * 0.5f;
        float area_t = (tx1 - tx0) * (ty1 - ty0);   // rect-difference form (matches ref)
        float best = -1.f; int bi = 0;
        #pragma unroll
        for (int a = 0; a < NA; ++a) {
            float aw = anc[2 * a], ah = anc[2 * a + 1];
            float ax1 = aw * 0.5f, ay1 = ah * 0.5f;
            float ax0 = 0.f - ax1, ay0 = 0.f - ay1;
            float x0 = fmaxf(tx0, ax0), y0 = fmaxf(ty0, ay0);
            float x1 = fminf(tx1, ax1), y1 = fminf(ty1, ay1);
            float inter = (x0 < x1 && y0 < y1) ? (x1 - x0) * (y1 - y0) : 0.f;
            float area_a = (ax1 - ax0) * (ay1 - ay0);
            float uni = area_t + area_a - inter;
            float iou = inter / uni;
            if (iou > best) { best = iou; bi = a; }   // strict >: first max wins (jnp.argmax)
        }
        bool m = (best > 0.5f) && valid;
        if (m) {
            int cxi = (int)cx, cyi = (int)cy;
            key = (bi * g + cyi) * g + cxi;
            cand = true;
            // HOISTED gather: address known pre-dedup; issue now so the ~900-cycle
            // HBM latency overlaps the dedup scan below. Values used only if kept.
            const float* p = outp + ((((size_t)b * NA + bi) * g + cyi) * g + cxi) * 85;
            p0 = p[0]; p1 = p[1]; p2 = p[2]; p3 = p[3];
        }
    }

    // Scatter dedup, last-write-wins: lane j survives iff no lane j' > j maps to the
    // same cell. v_readlane (SALU path, ~5cy) instead of ds_bpermute __shfl (~30cy):
    // j is compile-time constant under full unroll, so readlane is legal and cheap.
    bool conflict = false;
    #pragma unroll
    for (int j = 1; j < NT; ++j) {
        int k2 = __builtin_amdgcn_readlane(key, j);
        conflict |= (lane < j) & (k2 == key);
    }
    bool kept = cand && !conflict;

    float d = 0.f;
    if (kept) {
        float dx = p0 - t0, dy = p1 - t1;
        float rw = 1.f / sqrtf(p2) - 1.f / sqrtf(t2);
        float rh = 1.f / sqrtf(p3) - 1.f / sqrtf(t3);
        d = dx * dx + dy * dy + rw * rw + rh * rh;
    }

    unsigned long long bal = __ballot(kept);
    int n = __popcll(bal);

    // full-wave butterfly reduce of d
    #pragma unroll
    for (int off = 32; off >= 1; off >>= 1)
        d += __shfl_xor(d, off, 64);

    if (lane == 0) {
        float r = (n > 0) ? d / (2.0f * (float)n) : 0.0f;
        unsigned bits = __float_as_uint(r);
        // publish: value first (relaxed), then complement tag (release) so an
        // acquire-load of the tag orders the value load on the reducer side.
        __hip_atomic_store(&wsu[2 * pair], bits,
                           __ATOMIC_RELAXED, __HIP_MEMORY_SCOPE_AGENT);
        __hip_atomic_store(&wsu[2 * pair + 1], ~bits,
                           __ATOMIC_RELEASE, __HIP_MEMORY_SCOPE_AGENT);
    }
}

extern "C" void kernel_launch(void* const* d_in, const int* in_sizes, int n_in,
                              void* d_out, int out_size, void* d_ws, size_t ws_size,
                              hipStream_t stream) {
    const float* out0 = (const float*)d_in[0];
    const float* anc0 = (const float*)d_in[1];
    const float* out1 = (const float*)d_in[2];
    const float* anc1 = (const float*)d_in[3];
    const float* out2 = (const float*)d_in[4];
    const float* anc2 = (const float*)d_in[5];
    const float* tgts = (const float*)d_in[6];

    boxloss_fused_kernel<<<NPAIR + 1, 64, 0, stream>>>(
        out0, anc0, out1, anc1, out2, anc2, tgts, (float*)d_ws, (float*)d_out);
}